// Round 1
// baseline (1510.113 us; speedup 1.0000x reference)
//
#include <hip/hip_runtime.h>
#include <math.h>

// ---------------------------------------------------------------------------
// Graph transformer: h=embed -> 3x {QKV gemm, edge-softmax attention (CSR pull),
// Wo gemm} -> MLP head. All fp32.
// ---------------------------------------------------------------------------

#define DM 128            // d_model
#define HEADS 4
#define DH 32             // d_head

// ---------------- embed: h = X + Seed*Wseed + D*Wdeg + C*Wclu ---------------
__global__ void embed_kernel(const float* __restrict__ X, const float* __restrict__ Seed,
                             const float* __restrict__ Dg, const float* __restrict__ Cl,
                             const float* __restrict__ Wseed, const float* __restrict__ Wdeg,
                             const float* __restrict__ Wclu, float* __restrict__ H, int n) {
    int i = blockIdx.x * blockDim.x + threadIdx.x;
    if (i >= n * DM) return;
    int nd = i >> 7, d = i & (DM - 1);
    H[i] = X[nd] + Seed[nd] * Wseed[d] + Dg[nd] * Wdeg[d] + Cl[nd] * Wclu[d];
}

// ---------------- CSR build -------------------------------------------------
__global__ void count_kernel(const int* __restrict__ edst, int* __restrict__ deg, int E) {
    int e = blockIdx.x * blockDim.x + threadIdx.x;
    if (e < E) atomicAdd(&deg[edst[e]], 1);
}

__global__ void scan1_kernel(const int* __restrict__ in, int* __restrict__ outv,
                             int* __restrict__ bsums, int n) {
    __shared__ int s[256];
    int t = threadIdx.x;
    int i = blockIdx.x * 256 + t;
    int v = (i < n) ? in[i] : 0;
    s[t] = v;
    __syncthreads();
    for (int off = 1; off < 256; off <<= 1) {
        int x = (t >= off) ? s[t - off] : 0;
        __syncthreads();
        s[t] += x;
        __syncthreads();
    }
    if (i < n) outv[i] = s[t];
    if (t == 255) bsums[blockIdx.x] = s[255];
}

__global__ void scan2_kernel(int* __restrict__ bsums, int nb) {
    __shared__ int s[256];
    int t = threadIdx.x;
    int v = (t < nb) ? bsums[t] : 0;
    s[t] = v;
    __syncthreads();
    for (int off = 1; off < 256; off <<= 1) {
        int x = (t >= off) ? s[t - off] : 0;
        __syncthreads();
        s[t] += x;
        __syncthreads();
    }
    if (t < nb) bsums[t] = s[t];
}

__global__ void scan3_kernel(const int* __restrict__ outv, const int* __restrict__ bsums,
                             int* __restrict__ ptr, int n) {
    int i = blockIdx.x * 256 + threadIdx.x;
    if (i == 0) ptr[0] = 0;
    if (i < n) {
        int add = (blockIdx.x > 0) ? bsums[blockIdx.x - 1] : 0;
        ptr[i + 1] = outv[i] + add;
    }
}

__global__ void scatter_kernel(const int* __restrict__ esrc, const int* __restrict__ edst,
                               const int* __restrict__ ptr, int* __restrict__ fill,
                               int* __restrict__ out, int E) {
    int e = blockIdx.x * blockDim.x + threadIdx.x;
    if (e >= E) return;
    int d = edst[e];
    int pos = ptr[d] + atomicAdd(&fill[d], 1);
    out[pos] = esrc[e];
}

// ---------------- GEMM: O[n x 128] = A[n x 128] @ W[128 x 128] --------------
// block: 256 threads; tile 64 rows x 64 cols (gridDim.y = 2 col halves).
// LDS: A-tile padded (64 x 132) + W half (128 x 64) = 65 KB -> 2 blocks/CU.
__global__ __launch_bounds__(256) void gemm128_kernel(const float* __restrict__ A,
                                                      const float* __restrict__ W,
                                                      float* __restrict__ O, int n) {
    __shared__ float sA[64 * 132];
    __shared__ float sW[128 * 64];
    int t = threadIdx.x;
    int row0 = blockIdx.x * 64;
    int c0 = blockIdx.y * 64;

    // stage A tile (64x128 f32 = 2048 float4)
#pragma unroll
    for (int p = 0; p < 8; p++) {
        int f = p * 256 + t;
        int r = f >> 5, c4 = f & 31;
        float4 val = make_float4(0.f, 0.f, 0.f, 0.f);
        int gr = row0 + r;
        if (gr < n) val = *reinterpret_cast<const float4*>(A + gr * DM + c4 * 4);
        *reinterpret_cast<float4*>(&sA[r * 132 + c4 * 4]) = val;
    }
    // stage W half (128x64 f32 = 2048 float4)
#pragma unroll
    for (int p = 0; p < 8; p++) {
        int f = p * 256 + t;
        int k = f >> 4, c4 = f & 15;
        float4 val = *reinterpret_cast<const float4*>(W + k * DM + c0 + c4 * 4);
        *reinterpret_cast<float4*>(&sW[k * 64 + c4 * 4]) = val;
    }
    __syncthreads();

    int rg = t >> 4, cg = t & 15;           // 16 x 16 thread grid, 4x4 outputs each
    const float* pa = &sA[rg * 4 * 132];
    float4 acc0 = make_float4(0.f, 0.f, 0.f, 0.f);
    float4 acc1 = acc0, acc2 = acc0, acc3 = acc0;
#pragma unroll 4
    for (int k = 0; k < DM; k++) {
        float a0 = pa[0 * 132 + k];
        float a1 = pa[1 * 132 + k];
        float a2 = pa[2 * 132 + k];
        float a3 = pa[3 * 132 + k];
        float4 w = *reinterpret_cast<const float4*>(&sW[k * 64 + cg * 4]);
        acc0.x += a0 * w.x; acc0.y += a0 * w.y; acc0.z += a0 * w.z; acc0.w += a0 * w.w;
        acc1.x += a1 * w.x; acc1.y += a1 * w.y; acc1.z += a1 * w.z; acc1.w += a1 * w.w;
        acc2.x += a2 * w.x; acc2.y += a2 * w.y; acc2.z += a2 * w.z; acc2.w += a2 * w.w;
        acc3.x += a3 * w.x; acc3.y += a3 * w.y; acc3.z += a3 * w.z; acc3.w += a3 * w.w;
    }
    float4 accs[4] = {acc0, acc1, acc2, acc3};
#pragma unroll
    for (int i = 0; i < 4; i++) {
        int gr = row0 + rg * 4 + i;
        if (gr < n) *reinterpret_cast<float4*>(O + gr * DM + c0 + cg * 4) = accs[i];
    }
}

// ---------------- attention: one wave per dst node, all 4 heads -------------
// lane l covers dims l and l+64. Scores via two 32-lane shfl reductions.
__global__ __launch_bounds__(256) void attn_kernel(const float* __restrict__ Q,
                                                   const float* __restrict__ K,
                                                   const float* __restrict__ V,
                                                   const int* __restrict__ ptr,
                                                   const int* __restrict__ esrc,
                                                   float* __restrict__ AGG, int n) {
    int w = threadIdx.x >> 6;
    int lane = threadIdx.x & 63;
    int node = blockIdx.x * 4 + w;
    if (node >= n) return;
    const float scale = 0.17677669529663687f;   // 1/sqrt(32)
    float q0 = Q[node * DM + lane] * scale;
    float q1 = Q[node * DM + 64 + lane] * scale;
    float m0 = -INFINITY, m1 = -INFINITY;
    float s0 = 0.f, s1 = 0.f;
    float acc0 = 0.f, acc1 = 0.f;
    int e0 = ptr[node], e1 = ptr[node + 1];
    for (int e = e0; e < e1; e++) {
        int src = esrc[e];
        const float* kp = K + src * DM;
        const float* vp = V + src * DM;
        float k0 = kp[lane], k1 = kp[64 + lane];
        float v0 = vp[lane], v1 = vp[64 + lane];
        float p0 = q0 * k0, p1 = q1 * k1;
#pragma unroll
        for (int off = 1; off < 32; off <<= 1) {
            p0 += __shfl_xor(p0, off, 64);
            p1 += __shfl_xor(p1, off, 64);
        }
        // p0: head0 (lanes 0-31) / head1 (lanes 32-63); p1: head2 / head3
        float mn0 = fmaxf(m0, p0);
        float sc0 = __expf(m0 - mn0);
        float w0 = __expf(p0 - mn0);
        s0 = s0 * sc0 + w0;
        acc0 = acc0 * sc0 + w0 * v0;
        m0 = mn0;
        float mn1 = fmaxf(m1, p1);
        float sc1 = __expf(m1 - mn1);
        float w1 = __expf(p1 - mn1);
        s1 = s1 * sc1 + w1;
        acc1 = acc1 * sc1 + w1 * v1;
        m1 = mn1;
    }
    AGG[node * DM + lane] = acc0 / (s0 + 1e-9f);
    AGG[node * DM + 64 + lane] = acc1 / (s1 + 1e-9f);
}

// ---------------- MLP head: out = relu(h@W1+b1)@W2 + b2 ---------------------
__global__ __launch_bounds__(256) void mlp_kernel(const float* __restrict__ H,
                                                  const float* __restrict__ W1,
                                                  const float* __restrict__ b1,
                                                  const float* __restrict__ W2,
                                                  const float* __restrict__ b2,
                                                  float* __restrict__ out, int n) {
    int w = threadIdx.x >> 6;
    int lane = threadIdx.x & 63;
    int node = blockIdx.x * 4 + w;
    if (node >= n) return;
    float za = b1[lane], zb = b1[64 + lane];
    const float* h = H + node * DM;
#pragma unroll 4
    for (int k = 0; k < DM; k++) {
        float hv = h[k];
        za += hv * W1[k * DM + lane];
        zb += hv * W1[k * DM + 64 + lane];
    }
    za = fmaxf(za, 0.f);
    zb = fmaxf(zb, 0.f);
    float partial = za * W2[lane] + zb * W2[64 + lane];
#pragma unroll
    for (int off = 1; off < 64; off <<= 1) partial += __shfl_xor(partial, off, 64);
    if (lane == 0) out[node] = partial + b2[0];
}

// ---------------------------------------------------------------------------
extern "C" void kernel_launch(void* const* d_in, const int* in_sizes, int n_in,
                              void* d_out, int out_size, void* d_ws, size_t ws_size,
                              hipStream_t stream) {
    const float* X    = (const float*)d_in[0];
    const float* Seed = (const float*)d_in[1];
    const float* Dg   = (const float*)d_in[2];
    const float* Cl   = (const float*)d_in[3];
    const int* esrc   = (const int*)d_in[4];
    const int* edst   = (const int*)d_in[5];
    const float* Wseed = (const float*)d_in[6];
    const float* Wdeg  = (const float*)d_in[7];
    const float* Wclu  = (const float*)d_in[8];
    const float* Wq = (const float*)d_in[9];
    const float* Wk = (const float*)d_in[10];
    const float* Wv = (const float*)d_in[11];
    const float* Wo = (const float*)d_in[12];
    const float* W1 = (const float*)d_in[13];
    const float* b1 = (const float*)d_in[14];
    const float* W2 = (const float*)d_in[15];
    const float* b2 = (const float*)d_in[16];
    float* out = (float*)d_out;

    int n = in_sizes[0];
    int E = in_sizes[4];

    // workspace layout (256B aligned blocks)
    char* p = (char*)d_ws;
    auto alloc = [&](size_t bytes) {
        void* r = (void*)p;
        p += (bytes + 255) & ~(size_t)255;
        return r;
    };
    float* buf0 = (float*)alloc((size_t)n * DM * 4);
    float* buf1 = (float*)alloc((size_t)n * DM * 4);
    float* buf2 = (float*)alloc((size_t)n * DM * 4);
    float* buf3 = (float*)alloc((size_t)n * DM * 4);
    int* deg    = (int*)alloc((size_t)n * 4);
    int* ptr    = (int*)alloc((size_t)(n + 1) * 4);
    int* ptrtmp = (int*)alloc((size_t)n * 4);
    int* bsums  = (int*)alloc(1024);
    int* fill   = (int*)alloc((size_t)n * 4);
    int* esrcs  = (int*)alloc((size_t)E * 4);
    (void)ws_size; (void)n_in; (void)out_size;

    // zero the atomic counters
    hipMemsetAsync(deg, 0, (size_t)n * 4, stream);
    hipMemsetAsync(fill, 0, (size_t)n * 4, stream);

    // embed
    {
        int total = n * DM;
        embed_kernel<<<(total + 255) / 256, 256, 0, stream>>>(X, Seed, Dg, Cl, Wseed, Wdeg,
                                                              Wclu, buf0, n);
    }
    // CSR build (counting sort by dst)
    int nb = (n + 255) / 256;
    count_kernel<<<(E + 255) / 256, 256, 0, stream>>>(edst, deg, E);
    scan1_kernel<<<nb, 256, 0, stream>>>(deg, ptrtmp, bsums, n);
    scan2_kernel<<<1, 256, 0, stream>>>(bsums, nb);
    scan3_kernel<<<nb, 256, 0, stream>>>(ptrtmp, bsums, ptr, n);
    scatter_kernel<<<(E + 255) / 256, 256, 0, stream>>>(esrc, edst, ptr, fill, esrcs, E);

    // 3 transformer layers; rotate buffers: X_=h/agg, Y_=q/h_next
    dim3 ggrid((n + 63) / 64, 2);
    int agrid = (n + 3) / 4;
    float* Xb = buf0;
    float* Yb = buf1;
    for (int i = 0; i < 3; i++) {
        const float* wq = Wq + (size_t)i * DM * DM;
        const float* wk = Wk + (size_t)i * DM * DM;
        const float* wv = Wv + (size_t)i * DM * DM;
        const float* wo = Wo + (size_t)i * DM * DM;
        gemm128_kernel<<<ggrid, 256, 0, stream>>>(Xb, wq, Yb, n);
        gemm128_kernel<<<ggrid, 256, 0, stream>>>(Xb, wk, buf2, n);
        gemm128_kernel<<<ggrid, 256, 0, stream>>>(Xb, wv, buf3, n);
        attn_kernel<<<agrid, 256, 0, stream>>>(Yb, buf2, buf3, ptr, esrcs, Xb, n);
        gemm128_kernel<<<ggrid, 256, 0, stream>>>(Xb, wo, Yb, n);
        // swap
        float* tmp = Xb; Xb = Yb; Yb = tmp;
    }
    // MLP head (h lives in Xb after the swap)
    mlp_kernel<<<agrid, 256, 0, stream>>>(Xb, W1, b1, W2, b2, out, n);
}